// Round 1
// baseline (223.608 us; speedup 1.0000x reference)
//
#include <hip/hip_runtime.h>
#include <math.h>

#define NB 8
#define H 64
#define W 64
#define C 128
#define G 8
#define GC 16
#define P 9
#define NPIX (NB * H * W)   // 32768
#define GPO (G * P * 2)     // 144
#define GP (G * P)          // 72

// ---------------- Kernel 1: x_proj = x @ w_in + b_in ----------------
#define K1_PIX 8
__global__ __launch_bounds__(128) void k_input_proj(
    const float* __restrict__ x, const float* __restrict__ w_in,
    const float* __restrict__ b_in, float* __restrict__ xproj)
{
    __shared__ float xs[K1_PIX][C];
    const int t = threadIdx.x;                 // channel 0..127
    const int base = blockIdx.x * K1_PIX;
    #pragma unroll
    for (int j = 0; j < K1_PIX; ++j)
        xs[j][t] = x[(base + j) * C + t];
    __syncthreads();

    float acc[K1_PIX];
    const float bv = b_in[t];
    #pragma unroll
    for (int j = 0; j < K1_PIX; ++j) acc[j] = bv;

    #pragma unroll 4
    for (int k = 0; k < C; ++k) {
        const float wv = w_in[k * C + t];
        #pragma unroll
        for (int j = 0; j < K1_PIX; ++j)
            acc[j] = fmaf(xs[j][k], wv, acc[j]);
    }
    #pragma unroll
    for (int j = 0; j < K1_PIX; ++j)
        xproj[(base + j) * C + t] = acc[j];
}

// ------- Kernel 2: dwconv+LN+GELU -> offset/mask -> softmax -> sample -> out_proj -------
#define K2_PIX 4
__global__ __launch_bounds__(256) void k_main(
    const float* __restrict__ x, const float* __restrict__ xproj,
    const float* __restrict__ dw_w, const float* __restrict__ dw_b,
    const float* __restrict__ ln_g, const float* __restrict__ ln_b,
    const float* __restrict__ w_off, const float* __restrict__ b_off,
    const float* __restrict__ w_msk, const float* __restrict__ b_msk,
    const float* __restrict__ w_out, const float* __restrict__ b_out,
    float* __restrict__ out)
{
    __shared__ float x1s[K2_PIX][C];     // dw-conv -> LN/GELU result
    __shared__ float offl[K2_PIX][GPO];  // offsets
    __shared__ float ml[K2_PIX][GP];     // mask logits -> softmax in place
    __shared__ float smp[K2_PIX][C];     // sampled features
    __shared__ float stats[K2_PIX][2];   // mu, rsig

    const int t = threadIdx.x;
    const int base = blockIdx.x * K2_PIX;

    // ---- phase 1: depthwise 3x3 conv (pad=1, zeros) ----
    for (int idx = t; idx < K2_PIX * C; idx += 256) {
        const int j = idx >> 7, c = idx & 127;
        const int pix = base + j;
        const int n = pix / (H * W);
        const int rem = pix % (H * W);
        const int y = rem / W, xc = rem % W;
        float acc = dw_b[c];
        #pragma unroll
        for (int ky = 0; ky < 3; ++ky) {
            const int yy = y + ky - 1;
            if (yy < 0 || yy >= H) continue;
            #pragma unroll
            for (int kx = 0; kx < 3; ++kx) {
                const int xx = xc + kx - 1;
                if (xx < 0 || xx >= W) continue;
                acc = fmaf(x[((n * H + yy) * W + xx) * C + c],
                           dw_w[(ky * 3 + kx) * C + c], acc);
            }
        }
        x1s[j][c] = acc;
    }
    __syncthreads();

    // ---- phase 2: LayerNorm stats (one wave per pixel) ----
    {
        const int wv = t >> 6, lane = t & 63;
        const float v1 = x1s[wv][lane], v2 = x1s[wv][lane + 64];
        float s = v1 + v2;
        float sq = v1 * v1 + v2 * v2;
        #pragma unroll
        for (int d = 32; d > 0; d >>= 1) {
            s += __shfl_xor(s, d);
            sq += __shfl_xor(sq, d);
        }
        if (lane == 0) {
            const float mu = s * (1.0f / C);
            const float var = sq * (1.0f / C) - mu * mu;
            stats[wv][0] = mu;
            stats[wv][1] = rsqrtf(var + 1e-6f);
        }
    }
    __syncthreads();

    // ---- phase 3: LN affine + exact GELU ----
    for (int idx = t; idx < K2_PIX * C; idx += 256) {
        const int j = idx >> 7, c = idx & 127;
        float v = (x1s[j][c] - stats[j][0]) * stats[j][1] * ln_g[c] + ln_b[c];
        x1s[j][c] = v * 0.5f * (1.0f + erff(v * 0.70710678118654752f));
    }
    __syncthreads();

    // ---- phase 4: offset (144) + mask-logit (72) GEMVs over K=128 ----
    if (t < GPO + GP) {
        float acc[K2_PIX];
        const float* wcol;
        int o, ldw;
        if (t < GPO) { o = t;       ldw = GPO; wcol = w_off; }
        else         { o = t - GPO; ldw = GP;  wcol = w_msk; }
        const float bv = (t < GPO) ? b_off[o] : b_msk[o];
        #pragma unroll
        for (int j = 0; j < K2_PIX; ++j) acc[j] = bv;
        #pragma unroll 4
        for (int k = 0; k < C; ++k) {
            const float wv = wcol[k * ldw + o];
            #pragma unroll
            for (int j = 0; j < K2_PIX; ++j)
                acc[j] = fmaf(x1s[j][k], wv, acc[j]);
        }
        if (t < GPO) {
            #pragma unroll
            for (int j = 0; j < K2_PIX; ++j) offl[j][o] = acc[j];
        } else {
            #pragma unroll
            for (int j = 0; j < K2_PIX; ++j) ml[j][o] = acc[j];
        }
    }
    __syncthreads();

    // ---- phase 5: softmax over the 9 points, per (pixel, group) ----
    if (t < K2_PIX * G) {
        const int j = t >> 3, g = t & 7;
        float* lg = &ml[j][g * P];
        float mx = lg[0];
        #pragma unroll
        for (int i = 1; i < P; ++i) mx = fmaxf(mx, lg[i]);
        float e[P], s = 0.f;
        #pragma unroll
        for (int i = 0; i < P; ++i) { e[i] = expf(lg[i] - mx); s += e[i]; }
        const float inv = 1.0f / s;
        #pragma unroll
        for (int i = 0; i < P; ++i) lg[i] = e[i] * inv;
    }
    __syncthreads();

    // ---- phase 6: deformable bilinear sampling (on unpadded x_proj) ----
    for (int idx = t; idx < K2_PIX * C; idx += 256) {
        const int j = idx >> 7, c = idx & 127;
        const int g = c >> 4;
        const int pix = base + j;
        const int n = pix / (H * W);
        const int rem = pix % (H * W);
        const int y = rem / W, xc = rem % W;
        const float* img = xproj + (size_t)n * H * W * C;
        float acc = 0.f;
        #pragma unroll
        for (int pp = 0; pp < P; ++pp) {
            const int dxk = pp / 3 - 1, dyk = pp % 3 - 1;   // x-major point order
            const float ux = (float)(xc + dxk) + offl[j][(g * P + pp) * 2 + 0];
            const float uy = (float)(y + dyk) + offl[j][(g * P + pp) * 2 + 1];
            const float m = ml[j][g * P + pp];
            const float fx = floorf(ux), fy = floorf(uy);
            const float wx = ux - fx, wy = uy - fy;
            const int x0 = (int)fx, y0 = (int)fy;
            float v00 = 0.f, v10 = 0.f, v01 = 0.f, v11 = 0.f;
            const bool xv0 = (x0 >= 0) & (x0 < W);
            const bool xv1 = (x0 + 1 >= 0) & (x0 + 1 < W);
            if (y0 >= 0 && y0 < H) {
                const float* row = img + ((size_t)y0 * W) * C + c;
                if (xv0) v00 = row[(size_t)x0 * C];
                if (xv1) v10 = row[(size_t)(x0 + 1) * C];
            }
            if (y0 + 1 >= 0 && y0 + 1 < H) {
                const float* row = img + ((size_t)(y0 + 1) * W) * C + c;
                if (xv0) v01 = row[(size_t)x0 * C];
                if (xv1) v11 = row[(size_t)(x0 + 1) * C];
            }
            const float vtop = v00 * (1.f - wx) + v10 * wx;
            const float vbot = v01 * (1.f - wx) + v11 * wx;
            acc = fmaf(m, vtop * (1.f - wy) + vbot * wy, acc);
        }
        smp[j][c] = acc;
    }
    __syncthreads();

    // ---- phase 7: output projection ----
    {
        const int o = t & 127, half = t >> 7;   // half in {0,1} -> pixels half, half+2
        float acc0 = b_out[o];
        float acc1 = acc0;
        #pragma unroll 4
        for (int k = 0; k < C; ++k) {
            const float wv = w_out[k * C + o];
            acc0 = fmaf(smp[half][k], wv, acc0);
            acc1 = fmaf(smp[half + 2][k], wv, acc1);
        }
        out[(base + half) * C + o] = acc0;
        out[(base + half + 2) * C + o] = acc1;
    }
}

extern "C" void kernel_launch(void* const* d_in, const int* in_sizes, int n_in,
                              void* d_out, int out_size, void* d_ws, size_t ws_size,
                              hipStream_t stream)
{
    const float* x     = (const float*)d_in[0];
    const float* w_in  = (const float*)d_in[1];
    const float* b_in  = (const float*)d_in[2];
    const float* dw_w  = (const float*)d_in[3];
    const float* dw_b  = (const float*)d_in[4];
    const float* ln_g  = (const float*)d_in[5];
    const float* ln_b  = (const float*)d_in[6];
    const float* w_off = (const float*)d_in[7];
    const float* b_off = (const float*)d_in[8];
    const float* w_msk = (const float*)d_in[9];
    const float* b_msk = (const float*)d_in[10];
    const float* w_out = (const float*)d_in[11];
    const float* b_out = (const float*)d_in[12];
    float* xproj = (float*)d_ws;               // 32768*128 floats = 16.8 MB
    float* out   = (float*)d_out;

    hipLaunchKernelGGL(k_input_proj, dim3(NPIX / K1_PIX), dim3(128), 0, stream,
                       x, w_in, b_in, xproj);
    hipLaunchKernelGGL(k_main, dim3(NPIX / K2_PIX), dim3(256), 0, stream,
                       x, xproj, dw_w, dw_b, ln_g, ln_b,
                       w_off, b_off, w_msk, b_msk, w_out, b_out, out);
}

// Round 2
// 103.524 us; speedup vs baseline: 2.1600x; 2.1600x over previous
//
#include <hip/hip_runtime.h>
#include <math.h>

#define NB 8
#define H 64
#define W 64
#define C 128
#define G 8
#define GC 16
#define P 9
#define NPIX (NB * H * W)     // 32768
#define N_OFF 144
#define N_MSK 72
#define NT_COMB 14            // 224 padded cols
#define PK_IN_ELEMS   (8 * 4 * 64 * 8)    // 16384
#define PK_COMB_ELEMS (14 * 4 * 64 * 8)   // 28672
#define PK_OUT_ELEMS  (8 * 4 * 64 * 8)    // 16384

using bf16x8 = __attribute__((ext_vector_type(8))) short;
using f32x4  = __attribute__((ext_vector_type(4))) float;

__device__ __forceinline__ short f2bf(float f) {
    union { float fv; unsigned u; } v; v.fv = f;
    unsigned r = v.u + 0x7fffu + ((v.u >> 16) & 1u);
    return (short)(r >> 16);
}

// ---------------- K0: pack weights into MFMA B-fragment order, bf16 --------
// B frag for (nt,kt): lane l, elem i -> k = kt*32 + (l>>4)*8 + i ; n = nt*16 + (l&15)
// packed index = ((nt*4 + kt)*64 + l)*8 + i
__global__ __launch_bounds__(256) void k_pack(
    const float* __restrict__ w_in, const float* __restrict__ w_off,
    const float* __restrict__ w_msk, const float* __restrict__ w_out,
    short* __restrict__ pk_in, short* __restrict__ pk_comb, short* __restrict__ pk_out)
{
    const int tid = blockIdx.x * 256 + threadIdx.x;
    int p, which;
    if (tid < PK_IN_ELEMS) { p = tid; which = 0; }
    else if (tid < PK_IN_ELEMS + PK_COMB_ELEMS) { p = tid - PK_IN_ELEMS; which = 1; }
    else if (tid < PK_IN_ELEMS + PK_COMB_ELEMS + PK_OUT_ELEMS) { p = tid - PK_IN_ELEMS - PK_COMB_ELEMS; which = 2; }
    else return;
    const int e = p & 7, lane = (p >> 3) & 63, kt = (p >> 9) & 3, nt = p >> 11;
    const int k = kt * 32 + (lane >> 4) * 8 + e;
    const int n = nt * 16 + (lane & 15);
    float v;
    if (which == 0) {
        v = w_in[k * C + n];
        pk_in[p] = f2bf(v);
    } else if (which == 1) {
        if (n < N_OFF) v = w_off[k * N_OFF + n];
        else if (n < N_OFF + N_MSK) v = w_msk[k * N_MSK + (n - N_OFF)];
        else v = 0.f;
        pk_comb[p] = f2bf(v);
    } else {
        v = w_out[k * C + n];
        pk_out[p] = f2bf(v);
    }
}

// ---------------- K1: x_proj = x @ w_in + b_in  (MFMA bf16) ----------------
__global__ __launch_bounds__(256) void k_inproj(
    const float* __restrict__ x, const short* __restrict__ pk_in,
    const float* __restrict__ b_in, float* __restrict__ xproj)
{
    __shared__ __align__(16) short xa[64 * C];     // bf16, XOR-swizzled rows
    const int t = threadIdx.x;
    const int base = blockIdx.x * 64;

    // stage + convert: thread -> pixel j = t>>2, channels c0 = (t&3)*32
    {
        const int j = t >> 2, c0 = (t & 3) * 32;
        const float* src = x + (size_t)(base + j) * C + c0;
        const int sw = (j & 7) << 4;
        #pragma unroll
        for (int ch = 0; ch < 4; ++ch) {
            f32x4 f0 = *(const f32x4*)(src + ch * 8);
            f32x4 f1 = *(const f32x4*)(src + ch * 8 + 4);
            bf16x8 pk;
            #pragma unroll
            for (int e2 = 0; e2 < 4; ++e2) { pk[e2] = f2bf(f0[e2]); pk[4 + e2] = f2bf(f1[e2]); }
            const int byte = j * 256 + ((c0 * 2 + ch * 16) ^ sw);
            *(bf16x8*)((char*)xa + byte) = pk;
        }
    }
    __syncthreads();

    const int w = t >> 6, l = t & 63;
    const int m = w * 16 + (l & 15);
    const int sw = (l & 7) << 4;   // (m&7) == (l&7)
    bf16x8 a[4];
    #pragma unroll
    for (int kt = 0; kt < 4; ++kt)
        a[kt] = *(const bf16x8*)((char*)xa + m * 256 + ((kt * 64 + (l >> 4) * 16) ^ sw));

    #pragma unroll
    for (int nt = 0; nt < 8; ++nt) {
        f32x4 acc = {0.f, 0.f, 0.f, 0.f};
        const short* bp = pk_in + nt * 2048 + l * 8;
        #pragma unroll
        for (int kt = 0; kt < 4; ++kt) {
            bf16x8 b = *(const bf16x8*)(bp + kt * 512);
            acc = __builtin_amdgcn_mfma_f32_16x16x32_bf16(a[kt], b, acc, 0, 0, 0);
        }
        const int col = nt * 16 + (l & 15);
        const float bias = b_in[col];
        const int row0 = base + w * 16 + (l >> 4) * 4;
        #pragma unroll
        for (int r = 0; r < 4; ++r)
            xproj[(size_t)(row0 + r) * C + col] = acc[r] + bias;
    }
}

// ---------------- K2: fused dwconv+LN+GELU -> off/mask MFMA -> softmax ------
// ---------------- -> sampling -> outproj MFMA  (block = one image row) -----
__global__ __launch_bounds__(256) void k_main(
    const float* __restrict__ x, const float* __restrict__ xproj,
    const float* __restrict__ dw_w, const float* __restrict__ dw_b,
    const float* __restrict__ ln_g, const float* __restrict__ ln_b,
    const short* __restrict__ pk_comb, const float* __restrict__ b_off,
    const float* __restrict__ b_msk, const short* __restrict__ pk_out,
    const float* __restrict__ b_out, float* __restrict__ out)
{
    __shared__ float dww[9 * C];
    __shared__ float dwb[C], lng[C], lnb[C];
    __shared__ float part[64 * 4 * 2];
    __shared__ float stats[64 * 2];
    __shared__ __align__(16) short x1s[64 * C];      // bf16 swizzled
    __shared__ __align__(16) short offl[64 * N_OFF]; // bf16 offsets
    __shared__ float ml[64 * N_MSK];                 // fp32 logits -> probs
    __shared__ __align__(16) short smp[64 * C];      // bf16 swizzled sampled

    const int t = threadIdx.x;
    const int bid = blockIdx.x;
    const int n = bid >> 6, y = bid & 63;
    const int base = bid * 64;

    // stage small params
    for (int i = t; i < 9 * C; i += 256) dww[i] = dw_w[i];
    if (t < C) { dwb[t] = dw_b[t]; lng[t] = ln_g[t]; lnb[t] = ln_b[t]; }
    __syncthreads();

    // ---- phase A: depthwise 3x3 (zeros pad) ----
    const int j = t & 63;            // pixel-in-row == x coordinate
    const int c0 = (t >> 6) * 32;    // channel chunk
    float a[32];
    #pragma unroll
    for (int cc = 0; cc < 32; ++cc) a[cc] = dwb[c0 + cc];
    #pragma unroll
    for (int ky = 0; ky < 3; ++ky) {
        const int yy = y + ky - 1;
        if (yy < 0 || yy >= H) continue;
        #pragma unroll
        for (int kx = 0; kx < 3; ++kx) {
            const int xx = j + kx - 1;
            if (xx < 0 || xx >= W) continue;
            const f32x4* xs4 = (const f32x4*)(x + ((size_t)(n * H + yy) * W + xx) * C + c0);
            const f32x4* ws4 = (const f32x4*)(dww + (ky * 3 + kx) * C + c0);
            #pragma unroll
            for (int q = 0; q < 8; ++q) {
                f32x4 xv = xs4[q], wv = ws4[q];
                #pragma unroll
                for (int e2 = 0; e2 < 4; ++e2)
                    a[q * 4 + e2] = fmaf(xv[e2], wv[e2], a[q * 4 + e2]);
            }
        }
    }
    // partial LN sums
    {
        float s = 0.f, sq = 0.f;
        #pragma unroll
        for (int cc = 0; cc < 32; ++cc) { s += a[cc]; sq = fmaf(a[cc], a[cc], sq); }
        part[(j * 4 + (t >> 6)) * 2 + 0] = s;
        part[(j * 4 + (t >> 6)) * 2 + 1] = sq;
    }
    __syncthreads();
    if (t < 64) {
        float S = 0.f, Q = 0.f;
        #pragma unroll
        for (int q = 0; q < 4; ++q) { S += part[(t * 4 + q) * 2]; Q += part[(t * 4 + q) * 2 + 1]; }
        const float mu = S * (1.f / C);
        const float va = Q * (1.f / C) - mu * mu;
        stats[t * 2] = mu;
        stats[t * 2 + 1] = rsqrtf(va + 1e-6f);
    }
    __syncthreads();
    // LN affine + GELU -> bf16 swizzled x1s
    {
        const float mu = stats[j * 2], rs = stats[j * 2 + 1];
        const int sw = (j & 7) << 4;
        #pragma unroll
        for (int ch = 0; ch < 4; ++ch) {
            bf16x8 pk;
            #pragma unroll
            for (int e2 = 0; e2 < 8; ++e2) {
                const int cc = ch * 8 + e2;
                float v = (a[cc] - mu) * rs * lng[c0 + cc] + lnb[c0 + cc];
                v = v * 0.5f * (1.f + erff(v * 0.70710678118654752f));
                pk[e2] = f2bf(v);
            }
            const int byte = j * 256 + ((c0 * 2 + ch * 16) ^ sw);
            *(bf16x8*)((char*)x1s + byte) = pk;
        }
    }
    __syncthreads();

    // ---- phase B: offset(144) + mask(72) via MFMA, N padded to 224 ----
    {
        const int w = t >> 6, l = t & 63;
        const int m = w * 16 + (l & 15);
        const int sw = (l & 7) << 4;
        bf16x8 af[4];
        #pragma unroll
        for (int kt = 0; kt < 4; ++kt)
            af[kt] = *(const bf16x8*)((char*)x1s + m * 256 + ((kt * 64 + (l >> 4) * 16) ^ sw));
        const int pr0 = w * 16 + (l >> 4) * 4;
        #pragma unroll
        for (int nt = 0; nt < NT_COMB; ++nt) {
            f32x4 acc = {0.f, 0.f, 0.f, 0.f};
            const short* bp = pk_comb + nt * 2048 + l * 8;
            #pragma unroll
            for (int kt = 0; kt < 4; ++kt) {
                bf16x8 b = *(const bf16x8*)(bp + kt * 512);
                acc = __builtin_amdgcn_mfma_f32_16x16x32_bf16(af[kt], b, acc, 0, 0, 0);
            }
            const int col = nt * 16 + (l & 15);
            if (col < N_OFF) {
                const float bias = b_off[col];
                #pragma unroll
                for (int r = 0; r < 4; ++r)
                    offl[(pr0 + r) * N_OFF + col] = f2bf(acc[r] + bias);
            } else if (col < N_OFF + N_MSK) {
                const float bias = b_msk[col - N_OFF];
                #pragma unroll
                for (int r = 0; r < 4; ++r)
                    ml[(pr0 + r) * N_MSK + (col - N_OFF)] = acc[r] + bias;
            }
        }
    }
    __syncthreads();

    // ---- phase C: softmax over P per (pixel, group) ----
    #pragma unroll
    for (int it = 0; it < 2; ++it) {
        const int w2 = t + it * 256;
        const int px = w2 >> 3, g = w2 & 7;
        float* lg = ml + px * N_MSK + g * P;
        float mx = lg[0];
        #pragma unroll
        for (int i = 1; i < P; ++i) mx = fmaxf(mx, lg[i]);
        float e[P], s = 0.f;
        #pragma unroll
        for (int i = 0; i < P; ++i) { e[i] = expf(lg[i] - mx); s += e[i]; }
        const float inv = 1.0f / s;
        #pragma unroll
        for (int i = 0; i < P; ++i) lg[i] = e[i] * inv;
    }
    __syncthreads();

    // ---- phase D: deformable bilinear sampling ----
    const float* img = xproj + (size_t)n * H * W * C;
    #pragma unroll
    for (int it = 0; it < 2; ++it) {
        const int w2 = t + it * 256;
        const int px = w2 >> 3, g = w2 & 7;
        float acc16[16];
        #pragma unroll
        for (int q = 0; q < 16; ++q) acc16[q] = 0.f;
        #pragma unroll
        for (int p = 0; p < P; ++p) {
            const int both = *(const int*)((const char*)offl + px * (N_OFF * 2) + (g * P + p) * 4);
            const float offx = __uint_as_float(((unsigned)both) << 16);
            const float offy = __uint_as_float(((unsigned)both) & 0xffff0000u);
            const float mk = ml[px * N_MSK + g * P + p];
            const float ux = (float)(px + (p / 3) - 1) + offx;
            const float uy = (float)(y + (p % 3) - 1) + offy;
            const float fx = floorf(ux), fy = floorf(uy);
            const float wx = ux - fx, wy = uy - fy;
            const int x0 = (int)fx, y0 = (int)fy;
            float w00 = mk * (1.f - wx) * (1.f - wy);
            float w10 = mk * wx * (1.f - wy);
            float w01 = mk * (1.f - wx) * wy;
            float w11 = mk * wx * wy;
            if (!((x0 >= 0) & (x0 < W)))       { w00 = 0.f; w01 = 0.f; }
            if (!((x0 >= -1) & (x0 < W - 1)))  { w10 = 0.f; w11 = 0.f; }
            if (!((y0 >= 0) & (y0 < H)))       { w00 = 0.f; w10 = 0.f; }
            if (!((y0 >= -1) & (y0 < H - 1)))  { w01 = 0.f; w11 = 0.f; }
            const int x0c = min(max(x0, 0), W - 1), x1c = min(max(x0 + 1, 0), W - 1);
            const int y0c = min(max(y0, 0), H - 1), y1c = min(max(y0 + 1, 0), H - 1);
            const float* r0 = img + ((size_t)y0c * W) * C + g * GC;
            const float* r1 = img + ((size_t)y1c * W) * C + g * GC;
            const float* p00 = r0 + (size_t)x0c * C;
            const float* p10 = r0 + (size_t)x1c * C;
            const float* p01 = r1 + (size_t)x0c * C;
            const float* p11 = r1 + (size_t)x1c * C;
            #pragma unroll
            for (int q = 0; q < 4; ++q) {
                f32x4 v00 = *(const f32x4*)(p00 + q * 4);
                f32x4 v10 = *(const f32x4*)(p10 + q * 4);
                f32x4 v01 = *(const f32x4*)(p01 + q * 4);
                f32x4 v11 = *(const f32x4*)(p11 + q * 4);
                #pragma unroll
                for (int e2 = 0; e2 < 4; ++e2) {
                    float s2 = fmaf(w00, v00[e2], fmaf(w10, v10[e2],
                               fmaf(w01, v01[e2], w11 * v11[e2])));
                    acc16[q * 4 + e2] += s2;
                }
            }
        }
        // write 16 channels -> smp (bf16, swizzled)
        const int sw = (px & 7) << 4;
        #pragma unroll
        for (int ch = 0; ch < 2; ++ch) {
            bf16x8 pk;
            #pragma unroll
            for (int e2 = 0; e2 < 8; ++e2) pk[e2] = f2bf(acc16[ch * 8 + e2]);
            const int byte = px * 256 + ((g * 32 + ch * 16) ^ sw);
            *(bf16x8*)((char*)smp + byte) = pk;
        }
    }
    __syncthreads();

    // ---- phase E: output projection via MFMA ----
    {
        const int w = t >> 6, l = t & 63;
        const int m = w * 16 + (l & 15);
        const int sw = (l & 7) << 4;
        bf16x8 af[4];
        #pragma unroll
        for (int kt = 0; kt < 4; ++kt)
            af[kt] = *(const bf16x8*)((char*)smp + m * 256 + ((kt * 64 + (l >> 4) * 16) ^ sw));
        #pragma unroll
        for (int nt = 0; nt < 8; ++nt) {
            f32x4 acc = {0.f, 0.f, 0.f, 0.f};
            const short* bp = pk_out + nt * 2048 + l * 8;
            #pragma unroll
            for (int kt = 0; kt < 4; ++kt) {
                bf16x8 b = *(const bf16x8*)(bp + kt * 512);
                acc = __builtin_amdgcn_mfma_f32_16x16x32_bf16(af[kt], b, acc, 0, 0, 0);
            }
            const int col = nt * 16 + (l & 15);
            const float bias = b_out[col];
            const int row0 = base + w * 16 + (l >> 4) * 4;
            #pragma unroll
            for (int r = 0; r < 4; ++r)
                out[(size_t)(row0 + r) * C + col] = acc[r] + bias;
        }
    }
}

extern "C" void kernel_launch(void* const* d_in, const int* in_sizes, int n_in,
                              void* d_out, int out_size, void* d_ws, size_t ws_size,
                              hipStream_t stream)
{
    const float* x     = (const float*)d_in[0];
    const float* w_in  = (const float*)d_in[1];
    const float* b_in  = (const float*)d_in[2];
    const float* dw_w  = (const float*)d_in[3];
    const float* dw_b  = (const float*)d_in[4];
    const float* ln_g  = (const float*)d_in[5];
    const float* ln_b  = (const float*)d_in[6];
    const float* w_off = (const float*)d_in[7];
    const float* b_off = (const float*)d_in[8];
    const float* w_msk = (const float*)d_in[9];
    const float* b_msk = (const float*)d_in[10];
    const float* w_out = (const float*)d_in[11];
    const float* b_out = (const float*)d_in[12];

    short* pk_in   = (short*)d_ws;                       // 16384 shorts
    short* pk_comb = pk_in + PK_IN_ELEMS;                // 28672 shorts
    short* pk_out  = pk_comb + PK_COMB_ELEMS;            // 16384 shorts
    float* xproj   = (float*)((char*)d_ws + 2 * (PK_IN_ELEMS + PK_COMB_ELEMS + PK_OUT_ELEMS)); // 16.8 MB
    float* out     = (float*)d_out;

    hipLaunchKernelGGL(k_pack, dim3(240), dim3(256), 0, stream,
                       w_in, w_off, w_msk, w_out, pk_in, pk_comb, pk_out);
    hipLaunchKernelGGL(k_inproj, dim3(NPIX / 64), dim3(256), 0, stream,
                       x, pk_in, b_in, xproj);
    hipLaunchKernelGGL(k_main, dim3(NPIX / 64), dim3(256), 0, stream,
                       x, xproj, dw_w, dw_b, ln_g, ln_b,
                       pk_comb, b_off, b_msk, pk_out, b_out, out);
}